// Round 1
// baseline (149.295 us; speedup 1.0000x reference)
//
#include <hip/hip_runtime.h>
#include <math.h>

#define BB 8
#define SS 4096
#define DD 1024
#define KK 3072

// ---------------- Kernel 1: scores[b*S+s] = dot(x[b,s,:], w_router) ----------------
// One wave (64 lanes) per token row. 1024 floats = 256 float4; 4 float4/lane.
__global__ __launch_bounds__(256) void mod_scores(const float* __restrict__ x,
                                                  const float* __restrict__ w,
                                                  float* __restrict__ scores) {
    int wave = (int)((blockIdx.x * blockDim.x + threadIdx.x) >> 6);
    int lane = threadIdx.x & 63;
    if (wave >= BB * SS) return;
    const float4* xr = (const float4*)(x + (size_t)wave * DD);
    const float4* wr = (const float4*)w;
    float acc = 0.f;
#pragma unroll
    for (int i = 0; i < 4; ++i) {
        float4 a = xr[lane + 64 * i];
        float4 b = wr[lane + 64 * i];
        acc += a.x * b.x + a.y * b.y + a.z * b.z + a.w * b.w;
    }
#pragma unroll
    for (int off = 32; off > 0; off >>= 1)
        acc += __shfl_down(acc, off, 64);
    if (lane == 0) scores[wave] = acc;
}

// ---------------- Kernel 2: per-batch bitonic sort (descending) + softmax ----------
// One block (1024 threads) per batch row. LDS: 4096 scores + 4096 indices = 32 KB.
// rank_of[b*S + orig_idx] = sorted position (0 = highest score).
// weights[b*K + j] = softmax over top-K sorted scores.
__global__ __launch_bounds__(1024) void mod_sort(const float* __restrict__ scores,
                                                 int* __restrict__ rank_of,
                                                 float* __restrict__ weights) {
    __shared__ float ss[SS];
    __shared__ int   si[SS];
    __shared__ float red[1024];
    const int b = blockIdx.x;
    const int tid = threadIdx.x;

    for (int i = tid; i < SS; i += 1024) { ss[i] = scores[b * SS + i]; si[i] = i; }
    __syncthreads();

    // Bitonic sort into order defined by strict comparator:
    //   before(a,b) = (a.s > b.s) || (a.s == b.s && a.i < b.i)   [descending score]
    for (int k = 2; k <= SS; k <<= 1) {
        for (int j = k >> 1; j > 0; j >>= 1) {
            for (int i = tid; i < SS; i += 1024) {
                int ixj = i ^ j;
                if (ixj > i) {
                    float s1 = ss[i], s2 = ss[ixj];
                    int   i1 = si[i], i2 = si[ixj];
                    bool before = (s1 > s2) || (s1 == s2 && i1 < i2);
                    bool up = ((i & k) == 0);
                    // ascending segment wants 'before' element first
                    if (up ? !before : before) {
                        ss[i] = s2; ss[ixj] = s1;
                        si[i] = i2; si[ixj] = i1;
                    }
                }
            }
            __syncthreads();
        }
    }

    // softmax over top-K sorted scores (max is ss[0])
    float smax = ss[0];
    float part = 0.f;
    for (int i = tid; i < KK; i += 1024) part += expf(ss[i] - smax);
    red[tid] = part;
    __syncthreads();
    for (int off = 512; off > 0; off >>= 1) {
        if (tid < off) red[tid] += red[tid + off];
        __syncthreads();
    }
    float denom = red[0];

    for (int i = tid; i < SS; i += 1024) {
        rank_of[b * SS + si[i]] = i;
        if (i < KK) weights[b * KK + i] = expf(ss[i] - smax) / denom;
    }
}

// ---------------- Kernel 3: blend/copy per token row ------------------------------
// One block (256 threads) per (b,s) row; 256 x float4 = 1024 floats.
__global__ __launch_bounds__(256) void mod_blend(const float* __restrict__ x,
                                                 const float* __restrict__ proc,
                                                 const int* __restrict__ rank_of,
                                                 const float* __restrict__ weights,
                                                 float* __restrict__ out) {
    const int row = blockIdx.x;           // b*S + s
    const int b = row >> 12;              // / 4096
    const int t = threadIdx.x;
    const float4* xr = (const float4*)(x + (size_t)row * DD);
    float4* orow = (float4*)(out + (size_t)row * DD);
    const int j = rank_of[row];           // uniform per block -> scalar load
    float4 a = xr[t];
    if (j < KK) {
        float w = weights[b * KK + j];
        const float4* pr = (const float4*)(proc + ((size_t)b * KK + j) * DD);
        float4 p = pr[t];
        float4 o;
        o.x = p.x * w + (1.f - w) * a.x;
        o.y = p.y * w + (1.f - w) * a.y;
        o.z = p.z * w + (1.f - w) * a.z;
        o.w = p.w * w + (1.f - w) * a.w;
        orow[t] = o;
    } else {
        orow[t] = a;
    }
}

extern "C" void kernel_launch(void* const* d_in, const int* in_sizes, int n_in,
                              void* d_out, int out_size, void* d_ws, size_t ws_size,
                              hipStream_t stream) {
    const float* x    = (const float*)d_in[0];   // (B,S,D)
    const float* proc = (const float*)d_in[1];   // (B,K,D)
    const float* w    = (const float*)d_in[2];   // (D,)
    float* out = (float*)d_out;

    // workspace layout
    float* scores  = (float*)d_ws;                         // B*S floats   (128 KB)
    int*   rank_of = (int*)((char*)d_ws + BB * SS * 4);    // B*S ints     (128 KB)
    float* weights = (float*)((char*)d_ws + 2 * BB * SS * 4); // B*K floats (96 KB)

    // K1: 32768 rows, 4 waves/block -> 8192 blocks
    mod_scores<<<(BB * SS) / 4, 256, 0, stream>>>(x, w, scores);
    // K2: one block per batch row
    mod_sort<<<BB, 1024, 0, stream>>>(scores, rank_of, weights);
    // K3: one block per token row
    mod_blend<<<BB * SS, 256, 0, stream>>>(x, proc, rank_of, weights, out);
}